// Round 14
// baseline (1262.322 us; speedup 1.0000x reference)
//
#include <hip/hip_runtime.h>

// R13: REVERT to R10 (champion, 1258us = scan 1119 + prepass 137).
// R12's hand-unrolled 6-phase scan regressed 17% (VGPR 52->36: forced
// register reuse destroyed the compiler's schedule) — reverted.
// Scan: 656 cy/step = LDS-pipe (32x ds_read_b128 ~384cy) + VALU/trans
// (~350cy, overlapped) + dep tail + barrier. 12 structural variants tried;
// this body is the optimum. Prepass: fat-16 blocks, 137us (3.8 TB/s).

#define SEQ   4096
#define BATCH 256
#define DIN   64
#define DH    128
#define XSTEP (BATCH * DIN)
#define XP_BYTES ((size_t)SEQ * BATCH * DH * 2)

typedef _Float16 half8  __attribute__((ext_vector_type(8)));
typedef _Float16 half4v __attribute__((ext_vector_type(4)));
typedef _Float16 half2v __attribute__((ext_vector_type(2)));
typedef __fp16   fp16x2 __attribute__((ext_vector_type(2)));
typedef float    f32x4  __attribute__((ext_vector_type(4)));
typedef float    f32x2  __attribute__((ext_vector_type(2)));

union H2 { fp16x2 q; half2v h; unsigned int u; };

// tanh(x) = 1 - 2/(1 + e^{2x}); overflow-free for all finite x.
__device__ __forceinline__ float fast_tanh(float v) {
    float e = __builtin_amdgcn_exp2f(v * 2.88539008177792681472f);
    return 1.0f - 2.0f * __builtin_amdgcn_rcpf(e + 1.0f);
}

__device__ __forceinline__ half2v pk(float a, float b) {
    H2 u; u.q = __builtin_amdgcn_cvt_pkrtz(a, b);
    return u.h;
}

__device__ __forceinline__ half8 cvt8(f32x4 a, f32x4 b) {
    half2v p0 = pk(a[0], a[1]);
    half2v p1 = pk(a[2], a[3]);
    half2v p2 = pk(b[0], b[1]);
    half2v p3 = pk(b[2], b[3]);
    half8 r;
    r[0] = p0[0]; r[1] = p0[1]; r[2] = p1[0]; r[3] = p1[1];
    r[4] = p2[0]; r[5] = p2[1]; r[6] = p3[0]; r[7] = p3[1];
    return r;
}

__device__ __forceinline__ half4v pack4(f32x4 a) {
    half2v q0 = pk(a[0], a[1]);
    half2v q1 = pk(a[2], a[3]);
    half4v r;
    r[0] = q0[0]; r[1] = q0[1]; r[2] = q1[0]; r[3] = q1[1];
    return r;
}

__device__ __forceinline__ f32x4 cvt4f(half4v v) {
    f32x4 r;
    r[0] = (float)v[0]; r[1] = (float)v[1];
    r[2] = (float)v[2]; r[3] = (float)v[3];
    return r;
}

// byte offset of h[b][j] (f16) in a [16][128] tile; 16B-chunk XOR swizzle by b.
__device__ __forceinline__ int hoff(int b, int j) {
    return b * 256 + ((((j >> 3) ^ b) & 15) << 4) + (j & 7) * 2;
}

struct XSlot { f32x4 v0, v1, v2, v3; };
#define XLOAD(slot, p_) do {                                           \
        (slot).v0 = *(const f32x4*)(p_);                               \
        (slot).v1 = *(const f32x4*)((p_) + 4);                         \
        (slot).v2 = *(const f32x4*)((p_) + 32);                        \
        (slot).v3 = *(const f32x4*)((p_) + 36);                        \
    } while (0)

// ---------------------------------------------------------------------------
// Kernel 1: prepass GEMM, fat-16 blocks (R10, proven 137us).
// Block = 4 waves x 1024 rows; wave w handles rows [blk*1024 + w*256, +256)
// as 16 row-tiles of 16, weights loaded once, depth-2 x prefetch.
// ---------------------------------------------------------------------------
__launch_bounds__(256)
__global__ void rnn_prepass(const float* __restrict__ x,     // [SEQ*BATCH][DIN]
                            const float* __restrict__ Wih,   // [DH][DIN]
                            const float* __restrict__ bih,   // [DH]
                            const float* __restrict__ bhh,   // [DH]
                            _Float16* __restrict__ xp)       // [SEQ*BATCH][DH]
{
    const int tid  = threadIdx.x;
    const int w    = tid >> 6;
    const int lane = tid & 63;
    const int lb   = lane & 15;
    const int lg   = lane >> 4;
    const int wbase = blockIdx.x * 1024 + w * 256;   // this wave's 256-row span

    // A-frags: Wih for 8 j-subtiles x 2 k-halves (loaded ONCE per 256 rows)
    half8 A[8][2];
    #pragma unroll
    for (int s = 0; s < 8; ++s) {
        #pragma unroll
        for (int kt = 0; kt < 2; ++kt) {
            const float* wr = Wih + (s * 16 + lb) * DIN + kt * 32 + lg * 8;
            half8 f;
            #pragma unroll
            for (int i = 0; i < 8; ++i) f[i] = (_Float16)wr[i];
            A[s][kt] = f;
        }
    }
    f32x4 bias[8];
    #pragma unroll
    for (int s = 0; s < 8; ++s)
        #pragma unroll
        for (int r = 0; r < 4; ++r) {
            int j = s * 16 + lg * 4 + r;
            bias[s][r] = bih[j] + bhh[j];
        }

    // depth-2 software pipeline over 16 row-tiles
    XSlot ring[2];
    XLOAD(ring[0], x + (size_t)(wbase + 0 * 16 + lb) * DIN + lg * 8);
    XLOAD(ring[1], x + (size_t)(wbase + 1 * 16 + lb) * DIN + lg * 8);

    #pragma unroll
    for (int r = 0; r < 16; ++r) {
        const int row0 = wbase + r * 16;
        XSlot cur = ring[r & 1];                       // static under full unroll
        if (r + 2 < 16) {
            XLOAD(ring[r & 1], x + (size_t)(row0 + 32 + lb) * DIN + lg * 8);
        }
        half8 xf0 = cvt8(cur.v0, cur.v1);
        half8 xf1 = cvt8(cur.v2, cur.v3);

        _Float16* op = xp + (size_t)(row0 + lb) * DH + lg * 4;
        #pragma unroll
        for (int s = 0; s < 8; ++s) {
            f32x4 acc;
            acc = __builtin_amdgcn_mfma_f32_16x16x32_f16(A[s][0], xf0, bias[s], 0, 0, 0);
            acc = __builtin_amdgcn_mfma_f32_16x16x32_f16(A[s][1], xf1, acc,     0, 0, 0);
            *(half4v*)(op + s * 16) = pack4(acc);
        }
    }
}

// ---------------------------------------------------------------------------
// Kernel 2: the scan (R10 body, proven 1119us / 656 cy/step).
// ---------------------------------------------------------------------------
__launch_bounds__(512, 1)
__global__ void rnn_scan_xp(const _Float16* __restrict__ xp,  // [SEQ][BATCH][DH]
                            const float* __restrict__ Whh,    // [DH][DH]
                            float* __restrict__ out)          // [BATCH][DH]
{
    __shared__ __align__(16) char hbuf[8192];   // 2 x swizzled [16][128] f16

    const int tid   = threadIdx.x;
    const int wave  = tid >> 6;
    const int lane  = tid & 63;
    const int lb    = lane & 15;
    const int lg    = lane >> 4;
    const int bbase = blockIdx.x << 4;
    const int jbase = wave << 4;

    // persistent W_hh A-frags (K=128 -> 4)
    half8 Ahh[4];
    #pragma unroll
    for (int kt = 0; kt < 4; ++kt) {
        const float* wr = Whh + (jbase + lb) * DH + kt * 32 + lg * 8;
        half8 f;
        #pragma unroll
        for (int i = 0; i < 8; ++i) f[i] = (_Float16)wr[i];
        Ahh[kt] = f;
    }

    // xp ring: per lane 4 f16 = xp[t][bbase+lb][jbase + lg*4 .. +3]
    const _Float16* xpp = xp + (size_t)(bbase + lb) * DH + jbase + (lg << 2);
    const size_t XPS = (size_t)BATCH * DH;

    half4v xq1, xq2, xq3;
    f32x4 ci;   // f32 xp[t], C-in of chain 1
    {
        half4v x0 = *(const half4v*)(xpp);
        xq1 = *(const half4v*)(xpp + 1 * XPS);
        xq2 = *(const half4v*)(xpp + 2 * XPS);
        xq3 = *(const half4v*)(xpp + 3 * XPS);
        ci = cvt4f(x0);
    }
    const _Float16* xload = xpp + 4 * XPS;   // -> xp[min(t+4, SEQ-1)]

    half8 hf0, hf1, hf2, hf3;
    {
        half8 z;
        #pragma unroll
        for (int i = 0; i < 8; ++i) z[i] = (_Float16)0.0f;
        hf0 = hf1 = hf2 = hf3 = z;   // h_0 = 0
    }

    const int woff  = hoff(lb, jbase + (lg << 2));
    const int roff0 = hoff(lb, 0 * 32 + (lg << 3));
    const int roff1 = hoff(lb, 1 * 32 + (lg << 3));
    const int roff2 = hoff(lb, 2 * 32 + (lg << 3));
    const int roff3 = hoff(lb, 3 * 32 + (lg << 3));

    #pragma unroll 6
    for (int t = 0; t < SEQ - 1; ++t) {
        const int nb = (t + 1) & 1;   // compile-time under unroll-6
        char* hb = hbuf + nb * 4096;

        // hh: 2 independent depth-2 chains; chain1 C-in = xp[t] (+bias folded in)
        f32x4 zz = {0.0f, 0.0f, 0.0f, 0.0f};
        f32x4 acc1, acc2;
        acc1 = __builtin_amdgcn_mfma_f32_16x16x32_f16(Ahh[0], hf0, ci,   0, 0, 0);
        acc2 = __builtin_amdgcn_mfma_f32_16x16x32_f16(Ahh[2], hf2, zz,   0, 0, 0);
        acc1 = __builtin_amdgcn_mfma_f32_16x16x32_f16(Ahh[1], hf1, acc1, 0, 0, 0);
        acc2 = __builtin_amdgcn_mfma_f32_16x16x32_f16(Ahh[3], hf3, acc2, 0, 0, 0);

        // prefetch xp[t+4] (clamped at tail; extra loads of last row unused)
        half4v xnew = *(const half4v*)xload;
        if (t + 5 < SEQ) xload += XPS;

        // h_{t+1} = tanh(z) -> fp16 -> LDS
        f32x4 rA;
        #pragma unroll
        for (int r = 0; r < 4; ++r) rA[r] = fast_tanh(acc1[r] + acc2[r]);
        *(half4v*)(hb + woff) = pack4(rA);

        // rotate ring; ci <- xp[t+1] (off critical path)
        ci = cvt4f(xq1);
        xq1 = xq2; xq2 = xq3; xq3 = xnew;

        // publish h_{t+1}; manual lgkm-only drain (no vmcnt -> xp loads stay in flight)
        asm volatile("s_waitcnt lgkmcnt(0)" ::: "memory");
        __builtin_amdgcn_s_barrier();
        asm volatile("" ::: "memory");

        hf0 = *(const half8*)(hb + roff0);
        hf2 = *(const half8*)(hb + roff2);
        hf1 = *(const half8*)(hb + roff1);
        hf3 = *(const half8*)(hb + roff3);
    }

    // epilogue: t = SEQ-1 -> h_final -> out (f32)
    {
        f32x4 zz = {0.0f, 0.0f, 0.0f, 0.0f};
        f32x4 acc1, acc2;
        acc1 = __builtin_amdgcn_mfma_f32_16x16x32_f16(Ahh[0], hf0, ci,   0, 0, 0);
        acc2 = __builtin_amdgcn_mfma_f32_16x16x32_f16(Ahh[2], hf2, zz,   0, 0, 0);
        acc1 = __builtin_amdgcn_mfma_f32_16x16x32_f16(Ahh[1], hf1, acc1, 0, 0, 0);
        acc2 = __builtin_amdgcn_mfma_f32_16x16x32_f16(Ahh[3], hf3, acc2, 0, 0, 0);
        f32x4 rA;
        #pragma unroll
        for (int r = 0; r < 4; ++r) rA[r] = fast_tanh(acc1[r] + acc2[r]);
        *(f32x4*)(out + (size_t)(bbase + lb) * DH + jbase + (lg << 2)) = rA;
    }
}

// ---------------------------------------------------------------------------
// Fallback (R2 fused, proven 1768 us) if d_ws < 256 MB.
// ---------------------------------------------------------------------------
__device__ __forceinline__ int hoffc(int b, int chunk, int lo) {
    return b * 256 + ((chunk ^ b) << 4) + lo;
}
__device__ __forceinline__ int xoff_lds(int b, int chunk, int lo) {
    return b * 128 + (((chunk ^ (b & 7)) << 4) + lo);
}

__launch_bounds__(512, 1)
__global__ void rnn_fused_scan_r2(const float* __restrict__ x,
                                  const float* __restrict__ Wih,
                                  const float* __restrict__ bih,
                                  const float* __restrict__ Whh,
                                  const float* __restrict__ bhh,
                                  float* __restrict__ out)
{
    __shared__ __align__(16) char lds[12288];
    char* hbuf = lds;
    char* xbuf = lds + 8192;

    const int tid   = threadIdx.x;
    const int wave  = tid >> 6;
    const int lane  = tid & 63;
    const int lb    = lane & 15;
    const int lg    = lane >> 4;
    const int bbase = blockIdx.x << 4;
    const int jbase = wave << 4;

    half8 Ahh[4], Aih[2];
    #pragma unroll
    for (int kt = 0; kt < 4; ++kt) {
        const float* wr = Whh + (jbase + lb) * DH + kt * 32 + lg * 8;
        half8 f;
        #pragma unroll
        for (int i = 0; i < 8; ++i) f[i] = (_Float16)wr[i];
        Ahh[kt] = f;
    }
    #pragma unroll
    for (int kt = 0; kt < 2; ++kt) {
        const float* wr = Wih + (jbase + lb) * DIN + kt * 32 + lg * 8;
        half8 f;
        #pragma unroll
        for (int i = 0; i < 8; ++i) f[i] = (_Float16)wr[i];
        Aih[kt] = f;
    }
    f32x4 bias;
    #pragma unroll
    for (int r = 0; r < 4; ++r) {
        int j = jbase + lg * 4 + r;
        bias[r] = bih[j] + bhh[j];
    }

    const int bx = tid >> 5;
    const int kx = (tid & 31) << 1;
    const float* xlane = x + (size_t)(bbase + bx) * DIN + kx;

    f32x2 r0  = *(const f32x2*)(xlane + 0 * (size_t)XSTEP);
    f32x2 rx0 = *(const f32x2*)(xlane + 1 * (size_t)XSTEP);
    f32x2 rx1 = *(const f32x2*)(xlane + 2 * (size_t)XSTEP);
    f32x2 rx2 = *(const f32x2*)(xlane + 3 * (size_t)XSTEP);
    {
        half2v p; p[0] = (_Float16)r0[0]; p[1] = (_Float16)r0[1];
        *(half2v*)(xbuf + xoff_lds(bx, kx >> 3, (kx & 7) * 2)) = p;
    }
    const float* xload = xlane + 4 * (size_t)XSTEP;

    half8 hf0, hf1, hf2, hf3, xf0, xf1;
    {
        half8 z;
        #pragma unroll
        for (int i = 0; i < 8; ++i) z[i] = (_Float16)0.0f;
        hf0 = hf1 = hf2 = hf3 = z;
    }

    asm volatile("s_waitcnt lgkmcnt(0)" ::: "memory");
    __builtin_amdgcn_s_barrier();
    asm volatile("" ::: "memory");
    xf0 = *(const half8*)(xbuf + xoff_lds(lb, 0 * 4 + lg, 0));
    xf1 = *(const half8*)(xbuf + xoff_lds(lb, 1 * 4 + lg, 0));

    f32x4 acc_ih;
    acc_ih = __builtin_amdgcn_mfma_f32_16x16x32_f16(Aih[0], xf0, bias,   0, 0, 0);
    acc_ih = __builtin_amdgcn_mfma_f32_16x16x32_f16(Aih[1], xf1, acc_ih, 0, 0, 0);

    #pragma unroll 2
    for (int t = 0; t < SEQ - 1; ++t) {
        f32x4 zz = {0.0f, 0.0f, 0.0f, 0.0f};
        f32x4 acc1, acc2;
        acc1 = __builtin_amdgcn_mfma_f32_16x16x32_f16(Ahh[0], hf0, acc_ih, 0, 0, 0);
        acc2 = __builtin_amdgcn_mfma_f32_16x16x32_f16(Ahh[2], hf2, zz,     0, 0, 0);
        acc1 = __builtin_amdgcn_mfma_f32_16x16x32_f16(Ahh[1], hf1, acc1,   0, 0, 0);
        acc2 = __builtin_amdgcn_mfma_f32_16x16x32_f16(Ahh[3], hf3, acc2,   0, 0, 0);

        const int nb = (t + 1) & 1;
        {
            half2v p; p[0] = (_Float16)rx0[0]; p[1] = (_Float16)rx0[1];
            *(half2v*)(xbuf + nb * 2048 + xoff_lds(bx, kx >> 3, (kx & 7) * 2)) = p;
        }
        rx0 = rx1; rx1 = rx2;
        rx2 = *(const f32x2*)xload;
        if (t + 5 < SEQ) xload += XSTEP;

        f32x4 hv;
        #pragma unroll
        for (int r = 0; r < 4; ++r) hv[r] = fast_tanh(acc1[r] + acc2[r]);
        {
            half4v p;
            #pragma unroll
            for (int r = 0; r < 4; ++r) p[r] = (_Float16)hv[r];
            *(half4v*)(hbuf + nb * 4096 + hoffc(lb, (wave << 1) + (lg >> 1), (lg & 1) * 8)) = p;
        }

        asm volatile("s_waitcnt lgkmcnt(0)" ::: "memory");
        __builtin_amdgcn_s_barrier();
        asm volatile("" ::: "memory");

        hf0 = *(const half8*)(hbuf + nb * 4096 + hoffc(lb, 0 * 4 + lg, 0));
        hf2 = *(const half8*)(hbuf + nb * 4096 + hoffc(lb, 2 * 4 + lg, 0));
        hf1 = *(const half8*)(hbuf + nb * 4096 + hoffc(lb, 1 * 4 + lg, 0));
        hf3 = *(const half8*)(hbuf + nb * 4096 + hoffc(lb, 3 * 4 + lg, 0));
        xf0 = *(const half8*)(xbuf + nb * 2048 + xoff_lds(lb, 0 * 4 + lg, 0));
        xf1 = *(const half8*)(xbuf + nb * 2048 + xoff_lds(lb, 1 * 4 + lg, 0));

        acc_ih = __builtin_amdgcn_mfma_f32_16x16x32_f16(Aih[0], xf0, bias,   0, 0, 0);
        acc_ih = __builtin_amdgcn_mfma_f32_16x16x32_f16(Aih[1], xf1, acc_ih, 0, 0, 0);
    }

    {
        f32x4 zz = {0.0f, 0.0f, 0.0f, 0.0f};
        f32x4 acc1, acc2;
        acc1 = __builtin_amdgcn_mfma_f32_16x16x32_f16(Ahh[0], hf0, acc_ih, 0, 0, 0);
        acc2 = __builtin_amdgcn_mfma_f32_16x16x32_f16(Ahh[2], hf2, zz,     0, 0, 0);
        acc1 = __builtin_amdgcn_mfma_f32_16x16x32_f16(Ahh[1], hf1, acc1,   0, 0, 0);
        acc2 = __builtin_amdgcn_mfma_f32_16x16x32_f16(Ahh[3], hf3, acc2,   0, 0, 0);
        f32x4 res;
        #pragma unroll
        for (int r = 0; r < 4; ++r) res[r] = fast_tanh(acc1[r] + acc2[r]);
        *(f32x4*)(out + (size_t)(bbase + lb) * DH + jbase + (lg << 2)) = res;
    }
}

extern "C" void kernel_launch(void* const* d_in, const int* in_sizes, int n_in,
                              void* d_out, int out_size, void* d_ws, size_t ws_size,
                              hipStream_t stream) {
    const float* x   = (const float*)d_in[0];
    const float* Wih = (const float*)d_in[1];
    const float* bih = (const float*)d_in[2];
    const float* Whh = (const float*)d_in[3];
    const float* bhh = (const float*)d_in[4];
    float* out = (float*)d_out;

    if (ws_size >= XP_BYTES) {
        _Float16* xp = (_Float16*)d_ws;
        rnn_prepass<<<SEQ * BATCH / 1024, 256, 0, stream>>>(x, Wih, bih, bhh, xp);
        rnn_scan_xp<<<16, 512, 0, stream>>>(xp, Whh, out);
    } else {
        rnn_fused_scan_r2<<<16, 512, 0, stream>>>(x, Wih, bih, Whh, bhh, out);
    }
}

// Round 15
// 1258.804 us; speedup vs baseline: 1.0028x; 1.0028x over previous
//
#include <hip/hip_runtime.h>

// R13: REVERT to R10 (champion, 1258us = scan 1119 + prepass 137).
// R12's hand-unrolled 6-phase scan regressed 17% (VGPR 52->36: forced
// register reuse destroyed the compiler's schedule) — reverted.
// Scan: 656 cy/step = LDS-pipe (32x ds_read_b128 ~384cy) + VALU/trans
// (~350cy, overlapped) + dep tail + barrier. 12 structural variants tried;
// this body is the optimum. Prepass: fat-16 blocks, 137us (3.8 TB/s).

#define SEQ   4096
#define BATCH 256
#define DIN   64
#define DH    128
#define XSTEP (BATCH * DIN)
#define XP_BYTES ((size_t)SEQ * BATCH * DH * 2)

typedef _Float16 half8  __attribute__((ext_vector_type(8)));
typedef _Float16 half4v __attribute__((ext_vector_type(4)));
typedef _Float16 half2v __attribute__((ext_vector_type(2)));
typedef __fp16   fp16x2 __attribute__((ext_vector_type(2)));
typedef float    f32x4  __attribute__((ext_vector_type(4)));
typedef float    f32x2  __attribute__((ext_vector_type(2)));

union H2 { fp16x2 q; half2v h; unsigned int u; };

// tanh(x) = 1 - 2/(1 + e^{2x}); overflow-free for all finite x.
__device__ __forceinline__ float fast_tanh(float v) {
    float e = __builtin_amdgcn_exp2f(v * 2.88539008177792681472f);
    return 1.0f - 2.0f * __builtin_amdgcn_rcpf(e + 1.0f);
}

__device__ __forceinline__ half2v pk(float a, float b) {
    H2 u; u.q = __builtin_amdgcn_cvt_pkrtz(a, b);
    return u.h;
}

__device__ __forceinline__ half8 cvt8(f32x4 a, f32x4 b) {
    half2v p0 = pk(a[0], a[1]);
    half2v p1 = pk(a[2], a[3]);
    half2v p2 = pk(b[0], b[1]);
    half2v p3 = pk(b[2], b[3]);
    half8 r;
    r[0] = p0[0]; r[1] = p0[1]; r[2] = p1[0]; r[3] = p1[1];
    r[4] = p2[0]; r[5] = p2[1]; r[6] = p3[0]; r[7] = p3[1];
    return r;
}

__device__ __forceinline__ half4v pack4(f32x4 a) {
    half2v q0 = pk(a[0], a[1]);
    half2v q1 = pk(a[2], a[3]);
    half4v r;
    r[0] = q0[0]; r[1] = q0[1]; r[2] = q1[0]; r[3] = q1[1];
    return r;
}

__device__ __forceinline__ f32x4 cvt4f(half4v v) {
    f32x4 r;
    r[0] = (float)v[0]; r[1] = (float)v[1];
    r[2] = (float)v[2]; r[3] = (float)v[3];
    return r;
}

// byte offset of h[b][j] (f16) in a [16][128] tile; 16B-chunk XOR swizzle by b.
__device__ __forceinline__ int hoff(int b, int j) {
    return b * 256 + ((((j >> 3) ^ b) & 15) << 4) + (j & 7) * 2;
}

struct XSlot { f32x4 v0, v1, v2, v3; };
#define XLOAD(slot, p_) do {                                           \
        (slot).v0 = *(const f32x4*)(p_);                               \
        (slot).v1 = *(const f32x4*)((p_) + 4);                         \
        (slot).v2 = *(const f32x4*)((p_) + 32);                        \
        (slot).v3 = *(const f32x4*)((p_) + 36);                        \
    } while (0)

// ---------------------------------------------------------------------------
// Kernel 1: prepass GEMM, fat-16 blocks (R10, proven 137us).
// Block = 4 waves x 1024 rows; wave w handles rows [blk*1024 + w*256, +256)
// as 16 row-tiles of 16, weights loaded once, depth-2 x prefetch.
// ---------------------------------------------------------------------------
__launch_bounds__(256)
__global__ void rnn_prepass(const float* __restrict__ x,     // [SEQ*BATCH][DIN]
                            const float* __restrict__ Wih,   // [DH][DIN]
                            const float* __restrict__ bih,   // [DH]
                            const float* __restrict__ bhh,   // [DH]
                            _Float16* __restrict__ xp)       // [SEQ*BATCH][DH]
{
    const int tid  = threadIdx.x;
    const int w    = tid >> 6;
    const int lane = tid & 63;
    const int lb   = lane & 15;
    const int lg   = lane >> 4;
    const int wbase = blockIdx.x * 1024 + w * 256;   // this wave's 256-row span

    // A-frags: Wih for 8 j-subtiles x 2 k-halves (loaded ONCE per 256 rows)
    half8 A[8][2];
    #pragma unroll
    for (int s = 0; s < 8; ++s) {
        #pragma unroll
        for (int kt = 0; kt < 2; ++kt) {
            const float* wr = Wih + (s * 16 + lb) * DIN + kt * 32 + lg * 8;
            half8 f;
            #pragma unroll
            for (int i = 0; i < 8; ++i) f[i] = (_Float16)wr[i];
            A[s][kt] = f;
        }
    }
    f32x4 bias[8];
    #pragma unroll
    for (int s = 0; s < 8; ++s)
        #pragma unroll
        for (int r = 0; r < 4; ++r) {
            int j = s * 16 + lg * 4 + r;
            bias[s][r] = bih[j] + bhh[j];
        }

    // depth-2 software pipeline over 16 row-tiles
    XSlot ring[2];
    XLOAD(ring[0], x + (size_t)(wbase + 0 * 16 + lb) * DIN + lg * 8);
    XLOAD(ring[1], x + (size_t)(wbase + 1 * 16 + lb) * DIN + lg * 8);

    #pragma unroll
    for (int r = 0; r < 16; ++r) {
        const int row0 = wbase + r * 16;
        XSlot cur = ring[r & 1];                       // static under full unroll
        if (r + 2 < 16) {
            XLOAD(ring[r & 1], x + (size_t)(row0 + 32 + lb) * DIN + lg * 8);
        }
        half8 xf0 = cvt8(cur.v0, cur.v1);
        half8 xf1 = cvt8(cur.v2, cur.v3);

        _Float16* op = xp + (size_t)(row0 + lb) * DH + lg * 4;
        #pragma unroll
        for (int s = 0; s < 8; ++s) {
            f32x4 acc;
            acc = __builtin_amdgcn_mfma_f32_16x16x32_f16(A[s][0], xf0, bias[s], 0, 0, 0);
            acc = __builtin_amdgcn_mfma_f32_16x16x32_f16(A[s][1], xf1, acc,     0, 0, 0);
            *(half4v*)(op + s * 16) = pack4(acc);
        }
    }
}

// ---------------------------------------------------------------------------
// Kernel 2: the scan (R10 body, proven 1119us / 656 cy/step).
// ---------------------------------------------------------------------------
__launch_bounds__(512, 1)
__global__ void rnn_scan_xp(const _Float16* __restrict__ xp,  // [SEQ][BATCH][DH]
                            const float* __restrict__ Whh,    // [DH][DH]
                            float* __restrict__ out)          // [BATCH][DH]
{
    __shared__ __align__(16) char hbuf[8192];   // 2 x swizzled [16][128] f16

    const int tid   = threadIdx.x;
    const int wave  = tid >> 6;
    const int lane  = tid & 63;
    const int lb    = lane & 15;
    const int lg    = lane >> 4;
    const int bbase = blockIdx.x << 4;
    const int jbase = wave << 4;

    // persistent W_hh A-frags (K=128 -> 4)
    half8 Ahh[4];
    #pragma unroll
    for (int kt = 0; kt < 4; ++kt) {
        const float* wr = Whh + (jbase + lb) * DH + kt * 32 + lg * 8;
        half8 f;
        #pragma unroll
        for (int i = 0; i < 8; ++i) f[i] = (_Float16)wr[i];
        Ahh[kt] = f;
    }

    // xp ring: per lane 4 f16 = xp[t][bbase+lb][jbase + lg*4 .. +3]
    const _Float16* xpp = xp + (size_t)(bbase + lb) * DH + jbase + (lg << 2);
    const size_t XPS = (size_t)BATCH * DH;

    half4v xq1, xq2, xq3;
    f32x4 ci;   // f32 xp[t], C-in of chain 1
    {
        half4v x0 = *(const half4v*)(xpp);
        xq1 = *(const half4v*)(xpp + 1 * XPS);
        xq2 = *(const half4v*)(xpp + 2 * XPS);
        xq3 = *(const half4v*)(xpp + 3 * XPS);
        ci = cvt4f(x0);
    }
    const _Float16* xload = xpp + 4 * XPS;   // -> xp[min(t+4, SEQ-1)]

    half8 hf0, hf1, hf2, hf3;
    {
        half8 z;
        #pragma unroll
        for (int i = 0; i < 8; ++i) z[i] = (_Float16)0.0f;
        hf0 = hf1 = hf2 = hf3 = z;   // h_0 = 0
    }

    const int woff  = hoff(lb, jbase + (lg << 2));
    const int roff0 = hoff(lb, 0 * 32 + (lg << 3));
    const int roff1 = hoff(lb, 1 * 32 + (lg << 3));
    const int roff2 = hoff(lb, 2 * 32 + (lg << 3));
    const int roff3 = hoff(lb, 3 * 32 + (lg << 3));

    #pragma unroll 6
    for (int t = 0; t < SEQ - 1; ++t) {
        const int nb = (t + 1) & 1;   // compile-time under unroll-6
        char* hb = hbuf + nb * 4096;

        // hh: 2 independent depth-2 chains; chain1 C-in = xp[t] (+bias folded in)
        f32x4 zz = {0.0f, 0.0f, 0.0f, 0.0f};
        f32x4 acc1, acc2;
        acc1 = __builtin_amdgcn_mfma_f32_16x16x32_f16(Ahh[0], hf0, ci,   0, 0, 0);
        acc2 = __builtin_amdgcn_mfma_f32_16x16x32_f16(Ahh[2], hf2, zz,   0, 0, 0);
        acc1 = __builtin_amdgcn_mfma_f32_16x16x32_f16(Ahh[1], hf1, acc1, 0, 0, 0);
        acc2 = __builtin_amdgcn_mfma_f32_16x16x32_f16(Ahh[3], hf3, acc2, 0, 0, 0);

        // prefetch xp[t+4] (clamped at tail; extra loads of last row unused)
        half4v xnew = *(const half4v*)xload;
        if (t + 5 < SEQ) xload += XPS;

        // h_{t+1} = tanh(z) -> fp16 -> LDS
        f32x4 rA;
        #pragma unroll
        for (int r = 0; r < 4; ++r) rA[r] = fast_tanh(acc1[r] + acc2[r]);
        *(half4v*)(hb + woff) = pack4(rA);

        // rotate ring; ci <- xp[t+1] (off critical path)
        ci = cvt4f(xq1);
        xq1 = xq2; xq2 = xq3; xq3 = xnew;

        // publish h_{t+1}; manual lgkm-only drain (no vmcnt -> xp loads stay in flight)
        asm volatile("s_waitcnt lgkmcnt(0)" ::: "memory");
        __builtin_amdgcn_s_barrier();
        asm volatile("" ::: "memory");

        hf0 = *(const half8*)(hb + roff0);
        hf2 = *(const half8*)(hb + roff2);
        hf1 = *(const half8*)(hb + roff1);
        hf3 = *(const half8*)(hb + roff3);
    }

    // epilogue: t = SEQ-1 -> h_final -> out (f32)
    {
        f32x4 zz = {0.0f, 0.0f, 0.0f, 0.0f};
        f32x4 acc1, acc2;
        acc1 = __builtin_amdgcn_mfma_f32_16x16x32_f16(Ahh[0], hf0, ci,   0, 0, 0);
        acc2 = __builtin_amdgcn_mfma_f32_16x16x32_f16(Ahh[2], hf2, zz,   0, 0, 0);
        acc1 = __builtin_amdgcn_mfma_f32_16x16x32_f16(Ahh[1], hf1, acc1, 0, 0, 0);
        acc2 = __builtin_amdgcn_mfma_f32_16x16x32_f16(Ahh[3], hf3, acc2, 0, 0, 0);
        f32x4 rA;
        #pragma unroll
        for (int r = 0; r < 4; ++r) rA[r] = fast_tanh(acc1[r] + acc2[r]);
        *(f32x4*)(out + (size_t)(bbase + lb) * DH + jbase + (lg << 2)) = rA;
    }
}

// ---------------------------------------------------------------------------
// Fallback (R2 fused, proven 1768 us) if d_ws < 256 MB.
// ---------------------------------------------------------------------------
__device__ __forceinline__ int hoffc(int b, int chunk, int lo) {
    return b * 256 + ((chunk ^ b) << 4) + lo;
}
__device__ __forceinline__ int xoff_lds(int b, int chunk, int lo) {
    return b * 128 + (((chunk ^ (b & 7)) << 4) + lo);
}

__launch_bounds__(512, 1)
__global__ void rnn_fused_scan_r2(const float* __restrict__ x,
                                  const float* __restrict__ Wih,
                                  const float* __restrict__ bih,
                                  const float* __restrict__ Whh,
                                  const float* __restrict__ bhh,
                                  float* __restrict__ out)
{
    __shared__ __align__(16) char lds[12288];
    char* hbuf = lds;
    char* xbuf = lds + 8192;

    const int tid   = threadIdx.x;
    const int wave  = tid >> 6;
    const int lane  = tid & 63;
    const int lb    = lane & 15;
    const int lg    = lane >> 4;
    const int bbase = blockIdx.x << 4;
    const int jbase = wave << 4;

    half8 Ahh[4], Aih[2];
    #pragma unroll
    for (int kt = 0; kt < 4; ++kt) {
        const float* wr = Whh + (jbase + lb) * DH + kt * 32 + lg * 8;
        half8 f;
        #pragma unroll
        for (int i = 0; i < 8; ++i) f[i] = (_Float16)wr[i];
        Ahh[kt] = f;
    }
    #pragma unroll
    for (int kt = 0; kt < 2; ++kt) {
        const float* wr = Wih + (jbase + lb) * DIN + kt * 32 + lg * 8;
        half8 f;
        #pragma unroll
        for (int i = 0; i < 8; ++i) f[i] = (_Float16)wr[i];
        Aih[kt] = f;
    }
    f32x4 bias;
    #pragma unroll
    for (int r = 0; r < 4; ++r) {
        int j = jbase + lg * 4 + r;
        bias[r] = bih[j] + bhh[j];
    }

    const int bx = tid >> 5;
    const int kx = (tid & 31) << 1;
    const float* xlane = x + (size_t)(bbase + bx) * DIN + kx;

    f32x2 r0  = *(const f32x2*)(xlane + 0 * (size_t)XSTEP);
    f32x2 rx0 = *(const f32x2*)(xlane + 1 * (size_t)XSTEP);
    f32x2 rx1 = *(const f32x2*)(xlane + 2 * (size_t)XSTEP);
    f32x2 rx2 = *(const f32x2*)(xlane + 3 * (size_t)XSTEP);
    {
        half2v p; p[0] = (_Float16)r0[0]; p[1] = (_Float16)r0[1];
        *(half2v*)(xbuf + xoff_lds(bx, kx >> 3, (kx & 7) * 2)) = p;
    }
    const float* xload = xlane + 4 * (size_t)XSTEP;

    half8 hf0, hf1, hf2, hf3, xf0, xf1;
    {
        half8 z;
        #pragma unroll
        for (int i = 0; i < 8; ++i) z[i] = (_Float16)0.0f;
        hf0 = hf1 = hf2 = hf3 = z;
    }

    asm volatile("s_waitcnt lgkmcnt(0)" ::: "memory");
    __builtin_amdgcn_s_barrier();
    asm volatile("" ::: "memory");
    xf0 = *(const half8*)(xbuf + xoff_lds(lb, 0 * 4 + lg, 0));
    xf1 = *(const half8*)(xbuf + xoff_lds(lb, 1 * 4 + lg, 0));

    f32x4 acc_ih;
    acc_ih = __builtin_amdgcn_mfma_f32_16x16x32_f16(Aih[0], xf0, bias,   0, 0, 0);
    acc_ih = __builtin_amdgcn_mfma_f32_16x16x32_f16(Aih[1], xf1, acc_ih, 0, 0, 0);

    #pragma unroll 2
    for (int t = 0; t < SEQ - 1; ++t) {
        f32x4 zz = {0.0f, 0.0f, 0.0f, 0.0f};
        f32x4 acc1, acc2;
        acc1 = __builtin_amdgcn_mfma_f32_16x16x32_f16(Ahh[0], hf0, acc_ih, 0, 0, 0);
        acc2 = __builtin_amdgcn_mfma_f32_16x16x32_f16(Ahh[2], hf2, zz,     0, 0, 0);
        acc1 = __builtin_amdgcn_mfma_f32_16x16x32_f16(Ahh[1], hf1, acc1,   0, 0, 0);
        acc2 = __builtin_amdgcn_mfma_f32_16x16x32_f16(Ahh[3], hf3, acc2,   0, 0, 0);

        const int nb = (t + 1) & 1;
        {
            half2v p; p[0] = (_Float16)rx0[0]; p[1] = (_Float16)rx0[1];
            *(half2v*)(xbuf + nb * 2048 + xoff_lds(bx, kx >> 3, (kx & 7) * 2)) = p;
        }
        rx0 = rx1; rx1 = rx2;
        rx2 = *(const f32x2*)xload;
        if (t + 5 < SEQ) xload += XSTEP;

        f32x4 hv;
        #pragma unroll
        for (int r = 0; r < 4; ++r) hv[r] = fast_tanh(acc1[r] + acc2[r]);
        {
            half4v p;
            #pragma unroll
            for (int r = 0; r < 4; ++r) p[r] = (_Float16)hv[r];
            *(half4v*)(hbuf + nb * 4096 + hoffc(lb, (wave << 1) + (lg >> 1), (lg & 1) * 8)) = p;
        }

        asm volatile("s_waitcnt lgkmcnt(0)" ::: "memory");
        __builtin_amdgcn_s_barrier();
        asm volatile("" ::: "memory");

        hf0 = *(const half8*)(hbuf + nb * 4096 + hoffc(lb, 0 * 4 + lg, 0));
        hf2 = *(const half8*)(hbuf + nb * 4096 + hoffc(lb, 2 * 4 + lg, 0));
        hf1 = *(const half8*)(hbuf + nb * 4096 + hoffc(lb, 1 * 4 + lg, 0));
        hf3 = *(const half8*)(hbuf + nb * 4096 + hoffc(lb, 3 * 4 + lg, 0));
        xf0 = *(const half8*)(xbuf + nb * 2048 + xoff_lds(lb, 0 * 4 + lg, 0));
        xf1 = *(const half8*)(xbuf + nb * 2048 + xoff_lds(lb, 1 * 4 + lg, 0));

        acc_ih = __builtin_amdgcn_mfma_f32_16x16x32_f16(Aih[0], xf0, bias,   0, 0, 0);
        acc_ih = __builtin_amdgcn_mfma_f32_16x16x32_f16(Aih[1], xf1, acc_ih, 0, 0, 0);
    }

    {
        f32x4 zz = {0.0f, 0.0f, 0.0f, 0.0f};
        f32x4 acc1, acc2;
        acc1 = __builtin_amdgcn_mfma_f32_16x16x32_f16(Ahh[0], hf0, acc_ih, 0, 0, 0);
        acc2 = __builtin_amdgcn_mfma_f32_16x16x32_f16(Ahh[2], hf2, zz,     0, 0, 0);
        acc1 = __builtin_amdgcn_mfma_f32_16x16x32_f16(Ahh[1], hf1, acc1,   0, 0, 0);
        acc2 = __builtin_amdgcn_mfma_f32_16x16x32_f16(Ahh[3], hf3, acc2,   0, 0, 0);
        f32x4 res;
        #pragma unroll
        for (int r = 0; r < 4; ++r) res[r] = fast_tanh(acc1[r] + acc2[r]);
        *(f32x4*)(out + (size_t)(bbase + lb) * DH + jbase + (lg << 2)) = res;
    }
}

extern "C" void kernel_launch(void* const* d_in, const int* in_sizes, int n_in,
                              void* d_out, int out_size, void* d_ws, size_t ws_size,
                              hipStream_t stream) {
    const float* x   = (const float*)d_in[0];
    const float* Wih = (const float*)d_in[1];
    const float* bih = (const float*)d_in[2];
    const float* Whh = (const float*)d_in[3];
    const float* bhh = (const float*)d_in[4];
    float* out = (float*)d_out;

    if (ws_size >= XP_BYTES) {
        _Float16* xp = (_Float16*)d_ws;
        rnn_prepass<<<SEQ * BATCH / 1024, 256, 0, stream>>>(x, Wih, bih, bhh, xp);
        rnn_scan_xp<<<16, 512, 0, stream>>>(xp, Whh, out);
    } else {
        rnn_fused_scan_r2<<<16, 512, 0, stream>>>(x, Wih, bih, Whh, bhh, out);
    }
}